// Round 7
// baseline (87.516 us; speedup 1.0000x reference)
//
#include <hip/hip_runtime.h>
#include <hip/hip_bf16.h>

typedef __bf16 bf16_t;
typedef __bf16 bf16x8 __attribute__((ext_vector_type(8)));
typedef float f32x4 __attribute__((ext_vector_type(4)));

#define NB 1024
#define ND 32
#define VD 64
#define NH 256
#define NK 2048

// workspace layout (bytes)
#define OFF_A    0                       // 1024*2048 bf16 = 4 MB
#define OFF_W1T  (4u*1024u*1024u)        // 32*256*2048 bf16 = 32 MB
#define OFF_W2T  (36u*1024u*1024u)       // 32*64*256 bf16 = 1 MB

#define GLD16(gsrc, ldst) \
  __builtin_amdgcn_global_load_lds((const __attribute__((address_space(1))) void*)(gsrc), \
                                   (__attribute__((address_space(3))) void*)(ldst), 16, 0, 0)

// ---------------- prep (unchanged) ----------------
__global__ __launch_bounds__(256) void prep_kernel(
    const float* __restrict__ cv, const float* __restrict__ adj,
    const float* __restrict__ W1, const float* __restrict__ W2,
    bf16_t* __restrict__ A, bf16_t* __restrict__ W1T, bf16_t* __restrict__ W2T)
{
  __shared__ float Ls[64 * 67];
  int bx = blockIdx.x;
  int tid = threadIdx.x;
  if (bx < 4096) {
    int i = bx >> 7;
    int rem = bx & 127;
    int k0 = (rem >> 2) * 64;
    int h0 = (rem & 3) * 64;
    float a = adj[i * 32 + (k0 >> 6)];
    int rrow = tid >> 4, c4 = (tid & 15) * 4;
#pragma unroll
    for (int p = 0; p < 4; ++p) {
      int row = p * 16 + rrow;
      const float* src = W1 + ((size_t)(i * 2048 + k0 + row)) * 256 + h0 + c4;
      float4 v = *(const float4*)src;
#pragma unroll
      for (int j = 0; j < 4; ++j) Ls[row * 67 + c4 + j] = a * ((const float*)&v)[j];
    }
    __syncthreads();
#pragma unroll
    for (int p = 0; p < 2; ++p) {
      int u = p * 256 + tid;
      int h = u >> 3, c8 = u & 7;
      bf16x8 o;
#pragma unroll
      for (int j = 0; j < 8; ++j) o[j] = (bf16_t)Ls[(c8 * 8 + j) * 67 + h];
      *(bf16x8*)(W1T + ((size_t)(i * 256 + h0 + h)) * 2048 + k0 + c8 * 8) = o;
    }
  } else if (bx < 5120) {
    int t = (bx - 4096) * 256 + tid;
    const float4* s = (const float4*)cv + (size_t)t * 2;
    float4 v0 = s[0], v1 = s[1];
    bf16x8 o;
    o[0] = (bf16_t)v0.x; o[1] = (bf16_t)v0.y; o[2] = (bf16_t)v0.z; o[3] = (bf16_t)v0.w;
    o[4] = (bf16_t)v1.x; o[5] = (bf16_t)v1.y; o[6] = (bf16_t)v1.z; o[7] = (bf16_t)v1.w;
    *(bf16x8*)(A + (size_t)t * 8) = o;
  } else {
    int t = (bx - 5120) * 256 + tid;
    int i = t >> 11;
    int rem = t & 2047;
    int h8 = rem >> 6;
    int v = rem & 63;
    const float* src = W2 + ((size_t)(i * 256 + h8 * 8)) * 64 + v;
    bf16x8 o;
#pragma unroll
    for (int r = 0; r < 8; ++r) o[r] = (bf16_t)src[(size_t)r * 64];
    *(bf16x8*)(W2T + ((size_t)(i * 64 + v)) * 256 + h8 * 8) = o;
  }
}

// ------- fused main: 1024 blocks x 256 thr, 32x256 tile, BK=64, single-buffer, 4 blocks/CU -----
__global__ __launch_bounds__(256, 4) void sem_main_kernel(
    const bf16_t* __restrict__ A, const bf16_t* __restrict__ W1T,
    const bf16_t* __restrict__ W2T,
    const float* __restrict__ b1, const float* __restrict__ b2,
    const float* __restrict__ gamma, const float* __restrict__ beta,
    float* __restrict__ out)
{
  __shared__ char smem[36864];   // A [32][64] 4KB + B [256][64] 32KB; epilogue Hs [32][264] 16.9KB

  // XCD swizzle: 128 consecutive logical blocks (4 groups x 32 M-blocks) per XCD
  int p = blockIdx.x;
  int L = (p & 7) * 128 + (p >> 3);
  int i = L >> 5;           // group 0..31
  int brow = (L & 31) * 32; // M-block row

  int tid = threadIdx.x;
  int lane = tid & 63;
  int wid = tid >> 6;       // 0..3
  int wr = wid >> 1;        // 0..1  row half (16 rows)
  int wc = wid & 1;         // 0..1  col half (128 cols)
  int lhi = lane >> 4;      // 0..3
  int llo = lane & 15;

  const bf16_t* W1Ti = W1T + (size_t)i * 256 * 2048;

  // staging sources (pre-swizzled, G21): BK=64 -> 8 chunks/row, sc = c ^ (row&7)
  int arow = tid >> 3, ac = tid & 7;                 // row-in-32, chunk
  int sc0 = ac ^ (arow & 7);
  const bf16_t* aSrc = A + (size_t)(brow + arow) * 2048 + sc0 * 8;
  const bf16_t* bSrc = W1Ti + (size_t)arow * 2048 + sc0 * 8;   // + r*32 rows per round (row&7 invariant)
  int ldsW = wid * 1024;

  // stage tile kt into the single buffer: A 1 round, B 8 rounds (9 loads/thread)
  auto stage = [&](int kt) {
    GLD16(aSrc + (size_t)kt * 64, smem + ldsW);
#pragma unroll
    for (int r = 0; r < 8; ++r)
      GLD16(bSrc + (size_t)r * 65536 + (size_t)kt * 64, smem + 4096 + r * 4096 + ldsW);
  };

  // fragment LDS byte offsets (swizzled): addr = row*128 + ((kk*4+lhi)^(row&7))*16
  int arf = wr * 16 + llo;                  // A row 0..31
  int aOff[2];
#pragma unroll
  for (int kk = 0; kk < 2; ++kk)
    aOff[kk] = arf * 128 + (((kk * 4 + lhi) ^ (arf & 7)) * 16);
  int bOff[2][8];
#pragma unroll
  for (int n = 0; n < 8; ++n) {
    int brf = wc * 128 + n * 16 + llo;      // B row 0..255
#pragma unroll
    for (int kk = 0; kk < 2; ++kk)
      bOff[kk][n] = 4096 + brf * 128 + (((kk * 4 + lhi) ^ (brf & 7)) * 16);
  }

  f32x4 acc[8];
#pragma unroll
  for (int n = 0; n < 8; ++n) acc[n] = (f32x4){0.f, 0.f, 0.f, 0.f};

  stage(0);
  for (int t = 0; t < 32; ++t) {
    __syncthreads();                         // drains vmcnt -> tile t visible to all
#pragma unroll
    for (int kk = 0; kk < 2; ++kk) {
      bf16x8 af = *(const bf16x8*)(smem + aOff[kk]);
#pragma unroll
      for (int n = 0; n < 8; ++n) {
        bf16x8 bfr = *(const bf16x8*)(smem + bOff[kk][n]);
        acc[n] = __builtin_amdgcn_mfma_f32_16x16x32_bf16(af, bfr, acc[n], 0, 0, 0);
      }
    }
    __syncthreads();                         // all reads done before restage
    if (t < 31) stage(t + 1);
  }

  // ---- epilogue 1: bias + exact gelu -> Hs [32][264] bf16 ----
  bf16_t* Hs = (bf16_t*)smem;
#pragma unroll
  for (int n = 0; n < 8; ++n) {
    int col = wc * 128 + n * 16 + llo;
    float bias = b1[i * 256 + col];
#pragma unroll
    for (int r = 0; r < 4; ++r) {
      int row = wr * 16 + lhi * 4 + r;       // D: row=(lane>>4)*4+reg, col=lane&15
      float x = acc[n][r] + bias;
      float gl = 0.5f * x * (1.0f + erff(x * 0.70710678118654752f));
      Hs[row * 264 + col] = (bf16_t)gl;
    }
  }
  __syncthreads();

  // ---- GEMM2 + LN: waves 0-1 handle 16 rows each ----
  if (wid < 2) {
    f32x4 acc2[4];
#pragma unroll
    for (int n = 0; n < 4; ++n) acc2[n] = (f32x4){0.f, 0.f, 0.f, 0.f};
    const bf16_t* W2Ti = W2T + (size_t)i * 64 * 256;
#pragma unroll
    for (int kk = 0; kk < 8; ++kk) {
      int k = kk * 32 + lhi * 8;
      bf16x8 af = *(const bf16x8*)(Hs + (wid * 16 + llo) * 264 + k);
#pragma unroll
      for (int n = 0; n < 4; ++n) {
        bf16x8 bfr = *(const bf16x8*)(W2Ti + (size_t)(n * 16 + llo) * 256 + k);
        acc2[n] = __builtin_amdgcn_mfma_f32_16x16x32_bf16(af, bfr, acc2[n], 0, 0, 0);
      }
    }
    float b2v[4], gam[4], bet[4];
#pragma unroll
    for (int n = 0; n < 4; ++n) {
      int v = n * 16 + llo;
      b2v[n] = b2[i * 64 + v];
      gam[n] = gamma[i * 64 + v];
      bet[n] = beta[i * 64 + v];
    }
#pragma unroll
    for (int r = 0; r < 4; ++r) {
      float yv[4], s = 0.f, sq = 0.f;
#pragma unroll
      for (int n = 0; n < 4; ++n) {
        yv[n] = acc2[n][r] + b2v[n];
        s += yv[n];
        sq += yv[n] * yv[n];
      }
#pragma unroll
      for (int off = 1; off < 16; off <<= 1) {
        s += __shfl_xor(s, off, 64);
        sq += __shfl_xor(sq, off, 64);
      }
      float mu = s * (1.0f / 64.0f);
      float var = sq * (1.0f / 64.0f) - mu * mu;
      float rstd = rsqrtf(var + 1e-5f);
      int row = brow + wid * 16 + lhi * 4 + r;
      float* op = out + ((size_t)row * 32 + i) * 64;
#pragma unroll
      for (int n = 0; n < 4; ++n)
        op[n * 16 + llo] = (yv[n] - mu) * rstd * gam[n] + bet[n];
    }
  }
}

extern "C" void kernel_launch(void* const* d_in, const int* in_sizes, int n_in,
                              void* d_out, int out_size, void* d_ws, size_t ws_size,
                              hipStream_t stream) {
  const float* cv    = (const float*)d_in[0];
  const float* adj   = (const float*)d_in[1];
  const float* W1    = (const float*)d_in[2];
  const float* b1    = (const float*)d_in[3];
  const float* W2    = (const float*)d_in[4];
  const float* b2    = (const float*)d_in[5];
  const float* gamma = (const float*)d_in[6];
  const float* beta  = (const float*)d_in[7];
  float* out = (float*)d_out;

  bf16_t* Abf  = (bf16_t*)((char*)d_ws + OFF_A);
  bf16_t* W1T  = (bf16_t*)((char*)d_ws + OFF_W1T);
  bf16_t* W2T  = (bf16_t*)((char*)d_ws + OFF_W2T);

  prep_kernel<<<5376, 256, 0, stream>>>(cv, adj, W1, W2, Abf, W1T, W2T);
  sem_main_kernel<<<1024, 256, 0, stream>>>(Abf, W1T, W2T, b1, b2, gamma, beta, out);
}